// Round 6
// baseline (204.239 us; speedup 1.0000x reference)
//
#include <hip/hip_runtime.h>

typedef __attribute__((ext_vector_type(8))) short bf16x8;
typedef __attribute__((ext_vector_type(4))) float f32x4;
typedef __attribute__((ext_vector_type(4))) unsigned short u16x4;
typedef __attribute__((ext_vector_type(8))) unsigned short u16x8;

#define B_ 2048
#define A_ 50
#define H_ 512
#define NACT_ 64
#define F_ 562

// ws layout (bytes)
#define WS_W1T 0
#define WS_W2T ((size_t)A_ * H_ * H_ * 2)                    /* 26,214,400 */
#define WS_B1 (WS_W2T + (size_t)A_ * NACT_ * H_ * 2)         /* 29,491,200 */
#define WS_B2 (WS_B1 + (size_t)A_ * H_ * 4)                  /* 29,593,600 */
#define WS_H (WS_B2 + (size_t)A_ * NACT_ * 4)                /* 29,606,400 */
#define WS_NEED (WS_H + (size_t)B_ * A_ * H_ * 2)            /* 134,464,000 */

static __device__ __forceinline__ unsigned short f2bf(float f) {
  unsigned int u = __builtin_bit_cast(unsigned int, f);
  u += 0x7fffu + ((u >> 16) & 1u);
  return (unsigned short)(u >> 16);
}

static __device__ __forceinline__ void gld_lds16(const unsigned short* src,
                                                 unsigned short* dst) {
  __builtin_amdgcn_global_load_lds(
      (const __attribute__((address_space(1))) unsigned int*)(const void*)src,
      (__attribute__((address_space(3))) unsigned int*)(void*)dst, 16, 0, 0);
}

static __device__ __forceinline__ int clamp_r(int r) {
  return r < 0 ? 0 : (r > A_ - 1 ? A_ - 1 : r);
}

// ================= NEW PATH =================
// W1T layout: [a][slab s=k>>5 (16)][j 512][pos 4][e 8], 16B chunk at pos p
// holds logical within-slab chunk c = p ^ ((j>>1)&3)  (8-way bank spread at
// 64B row stride; involution).
__global__ void prep_w1_n(const float* __restrict__ w1,
                          const int* __restrict__ routing,
                          unsigned short* __restrict__ w1t) {
  const int bid = blockIdx.x;
  const int a = bid / 64;
  const int tile = bid - a * 64;
  const int tk = tile & 7, tj = tile >> 3;
  const int k0 = tk * 64, j0 = tj * 64;
  const int r = clamp_r(routing[a]);
  __shared__ float tl[64][65];
  const int t = threadIdx.x;
  const int c = t & 63, q = t >> 6;
#pragma unroll
  for (int i = 0; i < 16; ++i) {
    const int kl = q + i * 4;
    tl[kl][c] = w1[((size_t)r * F_ + k0 + kl) * H_ + j0 + c];
  }
  __syncthreads();
  const int jl = t >> 2, pq = t & 3;
  const int sx = (jl >> 1) & 3;
#pragma unroll
  for (int it = 0; it < 2; ++it) {
    const int cc = pq ^ sx; // logical chunk held at position pq
    u16x8 v;
#pragma unroll
    for (int e = 0; e < 8; ++e) v[e] = f2bf(tl[it * 32 + cc * 8 + e][jl]);
    unsigned short* dst =
        w1t + (((size_t)a * 16 + tk * 2 + it) * H_ + j0 + jl) * 32 + pq * 8;
    *(u16x8*)dst = v;
  }
}

// W2T layout: [a][slab s=k>>6 (8)][n 64][pos 8][e 8], pos p holds logical
// within-slab chunk c = p ^ (n&7).
__global__ void prep_w2_n(const float* __restrict__ w2,
                          const int* __restrict__ routing,
                          unsigned short* __restrict__ w2t) {
  const int bid = blockIdx.x;
  const int a = bid >> 3;
  const int tk = bid & 7;
  const int k0 = tk * 64;
  const int r = clamp_r(routing[a]);
  __shared__ float tl[64][65];
  const int t = threadIdx.x;
  const int c = t & 63, q = t >> 6;
#pragma unroll
  for (int i = 0; i < 16; ++i) {
    const int kl = q + i * 4;
    tl[kl][c] = w2[((size_t)r * H_ + k0 + kl) * NACT_ + c];
  }
  __syncthreads();
  const int n = t >> 2, pq0 = t & 3;
#pragma unroll
  for (int it = 0; it < 2; ++it) {
    const int p = it * 4 + pq0;
    const int cc = p ^ (n & 7);
    u16x8 v;
#pragma unroll
    for (int e = 0; e < 8; ++e) v[e] = f2bf(tl[cc * 8 + e][n]);
    unsigned short* dst =
        w2t + (((size_t)a * 8 + tk) * NACT_ + n) * 64 + p * 8;
    *(u16x8*)dst = v;
  }
}

__global__ void prep_bias(const float* __restrict__ w1,
                          const float* __restrict__ b1,
                          const float* __restrict__ b2,
                          const int* __restrict__ routing,
                          float* __restrict__ bias1, float* __restrict__ bias2) {
  const int a = blockIdx.x;
  const int t = threadIdx.x;
  const int r = clamp_r(routing[a]);
  bias1[a * H_ + t] = b1[(size_t)r * H_ + t] + w1[((size_t)r * F_ + H_ + a) * H_ + t];
  if (t < NACT_) bias2[a * NACT_ + t] = b2[r * NACT_ + t];
}

// K1: h[a][b][j] = relu(x(b,a,:) @ W1T(j,:) + bias1) ; tile 128m x 128j x K32
__global__ __launch_bounds__(256, 3) void k1_l1(
    const float* __restrict__ x, const unsigned short* __restrict__ w1t,
    const float* __restrict__ bias1, unsigned short* __restrict__ h_ws) {
  __shared__ union {
    struct {
      unsigned short w1s[2][128 * 32]; // [j_local][pos4][8], 2 x 8 KiB
      unsigned short xs[2][128 * 32];  // [m][pos4][8], 2 x 8 KiB
    } st;
    unsigned short hl[128 * 128]; // 32 KiB epilogue tile
  } sm;

  // 3200 blocks: swz = a*64 + mt*4 + jt  (jt innermost -> same-XCD share x)
  const int bid = blockIdx.x;
  const int swz = (bid & 7) * 400 + (bid >> 3);
  const int a = swz >> 6;
  const int rem = swz & 63;
  const int mt = rem >> 2, jt = rem & 3;
  const int b0 = mt * 128, j0g = jt * 128;

  const int tid = threadIdx.x;
  const int lane = tid & 63;
  const int w = tid >> 6; // 0..3
  const int l16 = lane & 15;
  const int lk = lane >> 4;
  const int sxor = lk ^ ((l16 >> 1) & 3);

  const int wj = (w & 1) * 64, wm = (w >> 1) * 64;

  const unsigned short* w1src =
      w1t + (size_t)a * (16 * H_ * 32) + (size_t)j0g * 32; // + slab*16384

  // x: row = tid>>1 (0..127), half = tid&1 (16 floats)
  const int xrow = tid >> 1, xhalf = tid & 1;
  const float* xp =
      x + ((size_t)(b0 + xrow) * A_ + (size_t)a) * H_ + xhalf * 16;
  const int xsrow = xrow * 32;
  const int xpos0 = (xhalf * 2) ^ ((xrow >> 1) & 3);

  const int afr_off = (wj + l16) * 32 + sxor * 8;
  const int bfr_off = (wm + l16) * 32 + sxor * 8;

  f32x4 acc[4][4];
#pragma unroll
  for (int i = 0; i < 4; ++i)
#pragma unroll
    for (int j = 0; j < 4; ++j) acc[i][j] = (f32x4){0.f, 0.f, 0.f, 0.f};

  // prologue: stage step 0
  {
    f32x4 xv[4];
#pragma unroll
    for (int i = 0; i < 4; ++i) xv[i] = *(const f32x4*)(xp + i * 4);
#pragma unroll
    for (int i = 0; i < 2; ++i) {
      const int idx = i * 256 + tid;
      gld_lds16(w1src + (size_t)(idx >> 2) * 32 + (idx & 3) * 8,
                sm.st.w1s[0] + idx * 8);
    }
    u16x8 v0, v1;
#pragma unroll
    for (int e = 0; e < 4; ++e) {
      v0[e] = f2bf(xv[0][e]); v0[4 + e] = f2bf(xv[1][e]);
      v1[e] = f2bf(xv[2][e]); v1[4 + e] = f2bf(xv[3][e]);
    }
    *(u16x8*)(sm.st.xs[0] + xsrow + xpos0 * 8) = v0;
    *(u16x8*)(sm.st.xs[0] + xsrow + (xpos0 ^ 1) * 8) = v1;
  }
  __syncthreads();

#pragma unroll 2
  for (int t = 0; t < 16; ++t) {
    const int buf = t & 1;
    f32x4 xv[4];
    if (t < 15) { // stage t+1: x to regs, W1 slab via global_load_lds
      const float* p = xp + (t + 1) * 32;
#pragma unroll
      for (int i = 0; i < 4; ++i) xv[i] = *(const f32x4*)(p + i * 4);
      const unsigned short* wsrc = w1src + (size_t)(t + 1) * (H_ * 32);
#pragma unroll
      for (int i = 0; i < 2; ++i) {
        const int idx = i * 256 + tid;
        gld_lds16(wsrc + (size_t)(idx >> 2) * 32 + (idx & 3) * 8,
                  sm.st.w1s[buf ^ 1] + idx * 8);
      }
    }
    // compute step t
    {
      const unsigned short* w1s = sm.st.w1s[buf];
      const unsigned short* xss = sm.st.xs[buf];
      bf16x8 afr[4], bfr[4];
#pragma unroll
      for (int jf = 0; jf < 4; ++jf)
        afr[jf] = *(const bf16x8*)(w1s + afr_off + jf * (16 * 32));
#pragma unroll
      for (int mf = 0; mf < 4; ++mf)
        bfr[mf] = *(const bf16x8*)(xss + bfr_off + mf * (16 * 32));
#pragma unroll
      for (int jf = 0; jf < 4; ++jf)
#pragma unroll
        for (int mf = 0; mf < 4; ++mf)
          acc[jf][mf] = __builtin_amdgcn_mfma_f32_16x16x32_bf16(
              afr[jf], bfr[mf], acc[jf][mf], 0, 0, 0);
    }
    if (t < 15) { // cvt + xs write for t+1
      u16x8 v0, v1;
#pragma unroll
      for (int e = 0; e < 4; ++e) {
        v0[e] = f2bf(xv[0][e]); v0[4 + e] = f2bf(xv[1][e]);
        v1[e] = f2bf(xv[2][e]); v1[4 + e] = f2bf(xv[3][e]);
      }
      *(u16x8*)(sm.st.xs[buf ^ 1] + xsrow + xpos0 * 8) = v0;
      *(u16x8*)(sm.st.xs[buf ^ 1] + xsrow + (xpos0 ^ 1) * 8) = v1;
    }
    __syncthreads();
  }

  // epilogue: relu+bias -> hl (chunk-XOR swizzled), then coalesced h_ws
  const float* b1p = bias1 + a * H_ + j0g;
#pragma unroll
  for (int jf = 0; jf < 4; ++jf) {
    const f32x4 bv = *(const f32x4*)(b1p + wj + jf * 16 + lk * 4);
    const int cJ = (wj >> 3) + jf * 2 + (lk >> 1);
    const int half4 = (lk & 1) * 4;
#pragma unroll
    for (int mf = 0; mf < 4; ++mf) {
      u16x4 hv;
#pragma unroll
      for (int r = 0; r < 4; ++r) {
        float f = acc[jf][mf][r] + bv[r];
        f = f > 0.f ? f : 0.f;
        hv[r] = f2bf(f);
      }
      const int m = wm + mf * 16 + l16;
      const int p = (cJ & 8) | ((cJ & 7) ^ (m & 7));
      *(u16x4*)(sm.hl + m * 128 + p * 8 + half4) = hv;
    }
  }
  __syncthreads();
  {
    const int m = tid >> 1, half = tid & 1;
    unsigned short* rowbase =
        h_ws + ((size_t)a * B_ + b0 + m) * H_ + (jt * 2 + half) * 64;
    const unsigned short* lsrc = sm.hl + m * 128 + half * 64;
#pragma unroll
    for (int p = 0; p < 8; ++p)
      *(u16x8*)(rowbase + p * 8) = *(const u16x8*)(lsrc + p * 8);
  }
}

// K2: out[b,a,n] = h(b,a,:) @ W2T(n,:) + b2 ; tile 128b x 64n x K64
__global__ __launch_bounds__(256, 3) void k2_l2(
    const unsigned short* __restrict__ h_ws,
    const unsigned short* __restrict__ w2t, const float* __restrict__ bias2,
    float* __restrict__ out) {
  __shared__ union {
    struct {
      unsigned short hA[2][128 * 64]; // [row][pos8][8], 2 x 16 KiB
      unsigned short wB[2][64 * 64];  // [n][pos8][8], 2 x 8 KiB
    } st;
    float outb[128][66];
  } sm;

  const int bid = blockIdx.x; // 800
  const int swz = (bid & 7) * 100 + (bid >> 3);
  const int a = swz >> 4;
  const int bt = swz & 15;
  const int b0 = bt * 128;

  const int tid = threadIdx.x;
  const int lane = tid & 63;
  const int w = tid >> 6;
  const int l16 = lane & 15;
  const int lk = lane >> 4;
  const int wm2 = w * 32;

  const unsigned short* hsrc = h_ws + ((size_t)a * B_ + b0) * H_;
  const unsigned short* wsrc = w2t + (size_t)a * 8 * (NACT_ * 64);

  f32x4 acc2[2][4];
#pragma unroll
  for (int i = 0; i < 2; ++i)
#pragma unroll
    for (int j = 0; j < 4; ++j) acc2[i][j] = (f32x4){0.f, 0.f, 0.f, 0.f};

  // prologue: stage slab 0
  {
#pragma unroll
    for (int i = 0; i < 4; ++i) {
      const int idx = i * 256 + tid;
      gld_lds16(hsrc + (size_t)(idx >> 3) * H_ + (idx & 7) * 8,
                sm.st.hA[0] + idx * 8);
    }
#pragma unroll
    for (int i = 0; i < 2; ++i) {
      const int idx = i * 256 + tid;
      gld_lds16(wsrc + (size_t)(idx >> 3) * 64 + (idx & 7) * 8,
                sm.st.wB[0] + idx * 8);
    }
  }
  __syncthreads();

#pragma unroll 2
  for (int s = 0; s < 8; ++s) {
    const int buf = s & 1;
    if (s < 7) {
      const unsigned short* hs = hsrc + (s + 1) * 64;
      const unsigned short* ws = wsrc + (size_t)(s + 1) * (NACT_ * 64);
#pragma unroll
      for (int i = 0; i < 4; ++i) {
        const int idx = i * 256 + tid;
        gld_lds16(hs + (size_t)(idx >> 3) * H_ + (idx & 7) * 8,
                  sm.st.hA[buf ^ 1] + idx * 8);
      }
#pragma unroll
      for (int i = 0; i < 2; ++i) {
        const int idx = i * 256 + tid;
        gld_lds16(ws + (size_t)(idx >> 3) * 64 + (idx & 7) * 8,
                  sm.st.wB[buf ^ 1] + idx * 8);
      }
    }
    const unsigned short* hA = sm.st.hA[buf];
    const unsigned short* wB = sm.st.wB[buf];
#pragma unroll
    for (int kk = 0; kk < 2; ++kk) {
      const int cxor = (kk * 4 + lk);
      bf16x8 afr[2], bfr[4];
#pragma unroll
      for (int mf = 0; mf < 2; ++mf) {
        const int row = wm2 + mf * 16 + l16;
        afr[mf] = *(const bf16x8*)(hA + row * 64 + (cxor ^ (l16 & 7)) * 8);
      }
#pragma unroll
      for (int nf = 0; nf < 4; ++nf) {
        const int n = nf * 16 + l16;
        bfr[nf] = *(const bf16x8*)(wB + n * 64 + (cxor ^ (l16 & 7)) * 8);
      }
#pragma unroll
      for (int mf = 0; mf < 2; ++mf)
#pragma unroll
        for (int nf = 0; nf < 4; ++nf)
          acc2[mf][nf] = __builtin_amdgcn_mfma_f32_16x16x32_bf16(
              afr[mf], bfr[nf], acc2[mf][nf], 0, 0, 0);
    }
    __syncthreads();
  }

  // epilogue
  float b2v[4];
#pragma unroll
  for (int nf = 0; nf < 4; ++nf)
    b2v[nf] = bias2[a * NACT_ + nf * 16 + l16];
#pragma unroll
  for (int mf = 0; mf < 2; ++mf)
#pragma unroll
    for (int nf = 0; nf < 4; ++nf)
#pragma unroll
      for (int r = 0; r < 4; ++r)
        sm.outb[wm2 + mf * 16 + lk * 4 + r][nf * 16 + l16] =
            acc2[mf][nf][r] + b2v[nf];
  __syncthreads();
  {
    const int row = tid >> 1, half = tid & 1;
    float* op = out + ((size_t)(b0 + row) * A_ + a) * NACT_ + half * 32;
#pragma unroll
    for (int i = 0; i < 8; ++i)
      *(f32x4*)(op + i * 4) = *(const f32x4*)(&sm.outb[row][half * 32 + i * 4]);
  }
}

// ================= FALLBACK (R4, verbatim) =================
__global__ void prep_w1_fb(const float* __restrict__ w1,
                           const int* __restrict__ routing,
                           unsigned short* __restrict__ w1t) {
  const int bid = blockIdx.x;
  const int a = bid / 64;
  const int tile = bid - a * 64;
  const int tk = tile & 7, tj = tile >> 3;
  const int k0 = tk * 64, j0 = tj * 64;
  const int r = clamp_r(routing[a]);
  __shared__ float tl[64][65];
  const int t = threadIdx.x;
  const int c = t & 63, q = t >> 6;
#pragma unroll
  for (int i = 0; i < 16; ++i) {
    const int kl = q + i * 4;
    tl[kl][c] = w1[((size_t)r * F_ + k0 + kl) * H_ + j0 + c];
  }
  __syncthreads();
#pragma unroll
  for (int it = 0; it < 2; ++it) {
    const int jl = t >> 2, c2 = t & 3;
    const int kc = it * 4 + (c2 ^ (jl & 3));
    u16x8 v;
#pragma unroll
    for (int e = 0; e < 8; ++e) v[e] = f2bf(tl[kc * 8 + e][jl]);
    unsigned short* dst = w1t +
        (((size_t)a * 16 + tk * 2 + it) * H_ + j0 + jl) * 32 + c2 * 8;
    *(u16x8*)dst = v;
  }
}

__global__ void prep_w2_fb(const float* __restrict__ w2,
                           const int* __restrict__ routing,
                           unsigned short* __restrict__ w2t) {
  const int bid = blockIdx.x;
  const int a = bid >> 3;
  const int tk = bid & 7;
  const int k0 = tk * 64;
  const int r = clamp_r(routing[a]);
  __shared__ float tl[64][65];
  const int t = threadIdx.x;
  const int c = t & 63, q = t >> 6;
#pragma unroll
  for (int i = 0; i < 16; ++i) {
    const int kl = q + i * 4;
    tl[kl][c] = w2[((size_t)r * H_ + k0 + kl) * NACT_ + c];
  }
  __syncthreads();
#pragma unroll
  for (int i = 0; i < 16; ++i) {
    const int nl = q + i * 4;
    w2t[((size_t)a * NACT_ + nl) * H_ + k0 + c] = f2bf(tl[c][nl]);
  }
}

__global__ __launch_bounds__(512, 4) void divtree_main_fb(
    const float* __restrict__ x, const unsigned short* __restrict__ w1t,
    const unsigned short* __restrict__ w2t, const float* __restrict__ bias1,
    const float* __restrict__ bias2, float* __restrict__ out) {
  __shared__ union {
    struct {
      unsigned short w1[2][H_ * 32];
      unsigned short xs[2][64 * 32];
    } st;
    unsigned short h[64 * H_];
    float outb[64][66];
  } sm;
  const int bid = blockIdx.x;
  const int swz = (bid & 7) * 200 + (bid >> 3);
  const int a = swz >> 5;
  const int mblk = swz & 31;
  const int b0 = mblk * 64;
  const int tid = threadIdx.x;
  const int lane = tid & 63;
  const int w = tid >> 6;
  const int l16 = lane & 15;
  const int lk = lane >> 4;
  const int sxor = lk ^ (l16 & 3);
  const int wj = w * 64;
  const unsigned short* w1ta = w1t + (size_t)a * (H_ * H_);
  const int xrow = tid >> 3;
  const int xq = tid & 7;
  const float* xbase =
      x + ((size_t)(b0 + xrow) * A_ + (size_t)a) * H_ + (size_t)xq * 4;
  const int xs_off = xrow * 32 + ((xq >> 1) ^ (xrow & 3)) * 8 + (xq & 1) * 4;
  const int afr_base = (wj + l16) * 32 + sxor * 8;
  const int bfr_base = l16 * 32 + sxor * 8;
  f32x4 acc[4][4];
#pragma unroll
  for (int i = 0; i < 4; ++i)
#pragma unroll
    for (int j = 0; j < 4; ++j) acc[i][j] = (f32x4){0.f, 0.f, 0.f, 0.f};
  f32x4 xr[3];
  {
    const f32x4 xv0 = *(const f32x4*)xbase;
#pragma unroll
    for (int i = 0; i < 4; ++i)
      gld_lds16(w1ta + ((size_t)(i * 512 + tid) << 3),
                sm.st.w1[0] + (size_t)(i * 512 + (w << 6)) * 8);
    xr[1] = *(const f32x4*)(xbase + 32);
    xr[2] = *(const f32x4*)(xbase + 64);
    u16x4 v;
#pragma unroll
    for (int e = 0; e < 4; ++e) v[e] = f2bf(xv0[e]);
    *(u16x4*)(sm.st.xs[0] + xs_off) = v;
  }
#pragma unroll
  for (int t = 0; t < 16; ++t) {
    const int buf = t & 1;
    if (t <= 13)
      asm volatile("s_waitcnt vmcnt(1) lgkmcnt(0)" ::: "memory");
    else
      asm volatile("s_waitcnt vmcnt(0) lgkmcnt(0)" ::: "memory");
    __builtin_amdgcn_sched_barrier(0);
    __builtin_amdgcn_s_barrier();
    __builtin_amdgcn_sched_barrier(0);
    if (t + 1 < 16) {
      const unsigned short* wsrc = w1ta + (size_t)(t + 1) * (H_ * 32);
      unsigned short* wdst = sm.st.w1[buf ^ 1];
#pragma unroll
      for (int i = 0; i < 4; ++i)
        gld_lds16(wsrc + ((size_t)(i * 512 + tid) << 3),
                  wdst + (size_t)(i * 512 + (w << 6)) * 8);
    }
    if (t + 3 < 16)
      xr[(t + 3) % 3] = *(const f32x4*)(xbase + (size_t)(t + 3) * 32);
    const unsigned short* w1s = sm.st.w1[buf];
    const unsigned short* xss = sm.st.xs[buf];
    bf16x8 bfr[4];
#pragma unroll
    for (int mf = 0; mf < 4; ++mf)
      bfr[mf] = *(const bf16x8*)(xss + bfr_base + mf * (16 * 32));
    __builtin_amdgcn_s_setprio(1);
#pragma unroll
    for (int jf = 0; jf < 4; ++jf) {
      const bf16x8 afr = *(const bf16x8*)(w1s + afr_base + jf * (16 * 32));
#pragma unroll
      for (int mf = 0; mf < 4; ++mf)
        acc[jf][mf] = __builtin_amdgcn_mfma_f32_16x16x32_bf16(
            afr, bfr[mf], acc[jf][mf], 0, 0, 0);
    }
    __builtin_amdgcn_s_setprio(0);
    if (t + 1 < 16) {
      const f32x4 xv = xr[(t + 1) % 3];
      u16x4 v;
#pragma unroll
      for (int e = 0; e < 4; ++e) v[e] = f2bf(xv[e]);
      *(u16x4*)(sm.st.xs[buf ^ 1] + xs_off) = v;
    }
  }
  __syncthreads();
  const float* b1p = bias1 + a * H_;
#pragma unroll
  for (int jf = 0; jf < 4; ++jf) {
    const f32x4 bv = *(const f32x4*)(b1p + wj + jf * 16 + lk * 4);
    const int cbase = (wj >> 3) + jf * 2 + (lk >> 1);
    const int half4 = (lk & 1) * 4;
#pragma unroll
    for (int mf = 0; mf < 4; ++mf) {
      u16x4 hv;
#pragma unroll
      for (int r = 0; r < 4; ++r) {
        float f = acc[jf][mf][r] + bv[r];
        f = f > 0.f ? f : 0.f;
        hv[r] = f2bf(f);
      }
      const int m = mf * 16 + l16;
      const int off = m * H_ + ((cbase ^ (l16 & 7))) * 8 + half4;
      *(u16x4*)(sm.h + off) = hv;
    }
  }
  __syncthreads();
  const int m0 = (w & 1) * 32;
  const int n0 = (w >> 1) * 16;
  const unsigned short* w2p =
      w2t + ((size_t)a * NACT_ + n0 + l16) * H_ + lk * 8;
  f32x4 acc2[2];
  acc2[0] = (f32x4){0.f, 0.f, 0.f, 0.f};
  acc2[1] = (f32x4){0.f, 0.f, 0.f, 0.f};
#pragma unroll
  for (int kf = 0; kf < 16; ++kf) {
    const bf16x8 bf2 = *(const bf16x8*)(w2p + kf * 32);
#pragma unroll
    for (int mf = 0; mf < 2; ++mf) {
      const int row = m0 + mf * 16 + l16;
      const int off = row * H_ + (((kf * 4 + lk) ^ (l16 & 7))) * 8;
      const bf16x8 af2 = *(const bf16x8*)(sm.h + off);
      acc2[mf] = __builtin_amdgcn_mfma_f32_16x16x32_bf16(af2, bf2, acc2[mf],
                                                         0, 0, 0);
    }
  }
  const float b2v = bias2[a * NACT_ + n0 + l16];
  __syncthreads();
#pragma unroll
  for (int mf = 0; mf < 2; ++mf)
#pragma unroll
    for (int r = 0; r < 4; ++r)
      sm.outb[m0 + mf * 16 + lk * 4 + r][n0 + l16] = acc2[mf][r] + b2v;
  __syncthreads();
  {
    const int row = tid >> 3;
    const int q8 = (tid & 7) * 8;
    const f32x4 v0 = *(const f32x4*)(&sm.outb[row][q8]);
    const f32x4 v1 = *(const f32x4*)(&sm.outb[row][q8 + 4]);
    float* op = out + ((size_t)(b0 + row) * A_ + a) * NACT_ + q8;
    *(f32x4*)op = v0;
    *(f32x4*)(op + 4) = v1;
  }
}

extern "C" void kernel_launch(void* const* d_in, const int* in_sizes, int n_in,
                              void* d_out, int out_size, void* d_ws,
                              size_t ws_size, hipStream_t stream) {
  const float* x = (const float*)d_in[0];
  const float* w1 = (const float*)d_in[1];
  const float* b1 = (const float*)d_in[2];
  const float* w2 = (const float*)d_in[3];
  const float* b2 = (const float*)d_in[4];
  const int* routing = (const int*)d_in[5];
  float* out = (float*)d_out;

  char* ws = (char*)d_ws;
  unsigned short* w1t = (unsigned short*)(ws + WS_W1T);
  unsigned short* w2t = (unsigned short*)(ws + WS_W2T);
  float* bias1 = (float*)(ws + WS_B1);
  float* bias2 = (float*)(ws + WS_B2);

  if (ws_size >= WS_NEED) {
    unsigned short* h_ws = (unsigned short*)(ws + WS_H);
    prep_w1_n<<<A_ * 64, 256, 0, stream>>>(w1, routing, w1t);
    prep_w2_n<<<A_ * 8, 256, 0, stream>>>(w2, routing, w2t);
    prep_bias<<<A_, 512, 0, stream>>>(w1, b1, b2, routing, bias1, bias2);
    k1_l1<<<A_ * 64, 256, 0, stream>>>(x, w1t, bias1, h_ws);
    k2_l2<<<A_ * 16, 256, 0, stream>>>(h_ws, w2t, bias2, out);
  } else {
    prep_w1_fb<<<A_ * 64, 256, 0, stream>>>(w1, routing, w1t);
    prep_w2_fb<<<A_ * 8, 256, 0, stream>>>(w2, routing, w2t);
    prep_bias<<<A_, 512, 0, stream>>>(w1, b1, b2, routing, bias1, bias2);
    divtree_main_fb<<<A_ * 32, 512, 0, stream>>>(x, w1t, w2t, bias1, bias2,
                                                 out);
  }
}